// Round 3
// baseline (693.411 us; speedup 1.0000x reference)
//
#include <hip/hip_runtime.h>
#include <math.h>

#define K_DIM 8192     // S*DIM
#define D_DIM 2048
#define M_ROWS 8192
#define N_W 32         // W columns (only 24 used)
#define NC 24          // used columns of H
#define BK 32          // k per staged chunk
#define RPB 256        // rows per block (= threads per block, thread-per-row)
#define KSPLIT 16
#define KRANGE (K_DIM / KSPLIT)   // 512 k per block
#define NCHUNK (KRANGE / BK)      // 16 chunks

// ---------------------------------------------------------------------------
// Kernel 1: partial GEMM  Hsum[m, n] += sum_{k in block's K-range} X[m,k]*W[k,n]
// Thread-per-row: lane owns a row -> W[k][0:24] is wave-uniform -> s_load
// (SGPR operand, no LDS, no VGPR). X is transposed through LDS:
//   - reg-stage global float4s coalesced, ds_write at slot (cc ^ (r&7))
//   - read own row with b128 at slot (j ^ (row&7))  [same involution]
// Double-buffered 2x32KB LDS, one barrier per chunk, prefetch into regs.
// Partials combined with fp32 atomicAdd into Hsum (zeroed by memset).
// ---------------------------------------------------------------------------
__global__ __launch_bounds__(256) void mhc_gemm_kernel(
    const float* __restrict__ X, const float* __restrict__ W,
    float* __restrict__ Hsum)
{
    __shared__ float4 tile[2 * RPB * (BK / 4)];   // 2 x 2048 float4 = 64 KB
    const int t = threadIdx.x;
    const int rowbase = blockIdx.x * RPB;
    const int kbase0 = blockIdx.y * KRANGE;

    float acc[NC];
#pragma unroll
    for (int n = 0; n < NC; ++n) acc[n] = 0.f;

    const float4* __restrict__ Xg = reinterpret_cast<const float4*>(X);
    float4 st[8];

    // ---- staging helpers (fully unrolled, static indexing) ----
    auto LOADREGS = [&](int c) {
        const int kb4 = (kbase0 + c * BK) >> 2;   // float4 col base
#pragma unroll
        for (int q = 0; q < 8; ++q) {
            const int f = q * 256 + t;            // tile float4 index
            const int r = f >> 3;                 // row within block
            const int cc = f & 7;                 // float4 slot within row
            st[q] = Xg[(size_t)(rowbase + r) * (K_DIM / 4) + kb4 + cc];
        }
    };
    auto WRITELDS = [&](int buf) {
        float4* dst = &tile[buf * (RPB * (BK / 4))];
#pragma unroll
        for (int q = 0; q < 8; ++q) {
            const int f = q * 256 + t;
            const int r = f >> 3;
            const int cc = f & 7;
            dst[r * 8 + (cc ^ (r & 7))] = st[q];
        }
    };

    LOADREGS(0);
    WRITELDS(0);
    int buf = 0;

    for (int c = 0; c < NCHUNK; ++c) {
        if (c + 1 < NCHUNK) LOADREGS(c + 1);      // prefetch next chunk
        __syncthreads();                          // tile[buf] ready

        // ---- compute: row t, k = kbase0 + c*BK + 4j + jj ----
        const float4* __restrict__ xt = &tile[buf * (RPB * (BK / 4)) + (t << 3)];
        const int sw = t & 7;
        const int kb = kbase0 + c * BK;
#pragma unroll
        for (int j = 0; j < 8; ++j) {
            const float4 xv = xt[j ^ sw];
            const float* xe = reinterpret_cast<const float*>(&xv);
#pragma unroll
            for (int jj = 0; jj < 4; ++jj) {
                const float x = xe[jj];
                const float* __restrict__ wr = W + (size_t)(kb + (j << 2) + jj) * N_W;
#pragma unroll
                for (int n = 0; n < NC; ++n)
                    acc[n] = fmaf(wr[n], x, acc[n]);   // wr[n] wave-uniform -> SGPR
            }
        }

        if (c + 1 < NCHUNK) WRITELDS(buf ^ 1);
        buf ^= 1;
    }

    float* hrow = Hsum + (size_t)(rowbase + t) * NC;
#pragma unroll
    for (int n = 0; n < NC; ++n) atomicAdd(hrow + n, acc[n]);
}

// ---------------------------------------------------------------------------
// Kernel 2: params (transform + sinkhorn) + apply. One block per row.
// Phase 0 (wave 0): lanes 0..23 read H[row][lane], transform; lanes 0..15 run
// 20-iter Sinkhorn on the 4x4 via shfl; params -> LDS.
// Phase 1: float4 streaming apply (unchanged from R2).
// ---------------------------------------------------------------------------
__global__ __launch_bounds__(256) void mhc_apply_kernel(
    const float* __restrict__ X, const float* __restrict__ Hsum,
    const float* __restrict__ ab, float* __restrict__ out)
{
    __shared__ float pbuf[NC];
    const int row = blockIdx.x;
    const int t = threadIdx.x;

    if (t < 64) {
        const int lane = t;
        const float pl = (lane < NC) ? Hsum[(size_t)row * NC + lane] : 0.f;
        const float bias  = (lane < NC) ? ab[lane] : 0.f;
        const float scale = ab[(lane < 16) ? 24 : ((lane < 20) ? 25 : 26)];

        float vout;
        if (lane < 16) {
            vout = __expf(fmaf(scale, pl, bias));                 // exp(a_res*H+b)
        } else {
            vout = fmaf(scale, 1.f / (1.f + __expf(-pl)), bias);  // a*sigmoid(H)+b
        }

        // Sinkhorn on lanes 0..15: lane = s*4 + i.
        float p = vout;
        for (int it = 0; it < 20; ++it) {
            float rs = p + __shfl_xor(p, 1);
            rs += __shfl_xor(rs, 2);
            p = p / rs;
            float cs = p + __shfl_xor(p, 4);
            cs += __shfl_xor(cs, 8);
            p = p / cs;
        }
        if (lane < NC) pbuf[lane] = (lane < 16) ? p : vout;
    }
    __syncthreads();

    float hres[4][4], hpre[4], hpos[4];
#pragma unroll
    for (int i = 0; i < 16; ++i) hres[i >> 2][i & 3] = pbuf[i];
#pragma unroll
    for (int i = 0; i < 4; ++i) hpre[i] = pbuf[16 + i];
#pragma unroll
    for (int i = 0; i < 4; ++i) hpos[i] = pbuf[20 + i];

    const float4* __restrict__ Xr =
        reinterpret_cast<const float4*>(X + (size_t)row * K_DIM);
    float4* __restrict__ Or = reinterpret_cast<float4*>(out + (size_t)row * K_DIM);

#pragma unroll
    for (int q = 0; q < 2; ++q) {
        const int pos = t + q * 256;          // float4 index within a 2048-seg
        float4 xq[4];
#pragma unroll
        for (int i = 0; i < 4; ++i) xq[i] = Xr[i * (D_DIM / 4) + pos];

        float y[4];
#pragma unroll
        for (int e = 0; e < 4; ++e) {
            float s = 0.f;
#pragma unroll
            for (int i = 0; i < 4; ++i)
                s = fmaf(hpre[i], reinterpret_cast<const float*>(&xq[i])[e], s);
            y[e] = s;
        }

#pragma unroll
        for (int s = 0; s < 4; ++s) {
            float4 o;
            float* oe = reinterpret_cast<float*>(&o);
#pragma unroll
            for (int e = 0; e < 4; ++e) {
                float v = hpos[s] * y[e];
#pragma unroll
                for (int i = 0; i < 4; ++i)
                    v = fmaf(hres[s][i], reinterpret_cast<const float*>(&xq[i])[e], v);
                oe[e] = v;
            }
            Or[s * (D_DIM / 4) + pos] = o;
        }
    }
}

extern "C" void kernel_launch(void* const* d_in, const int* in_sizes, int n_in,
                              void* d_out, int out_size, void* d_ws, size_t ws_size,
                              hipStream_t stream) {
    const float* X  = (const float*)d_in[0];
    const float* W  = (const float*)d_in[1];
    const float* ab = (const float*)d_in[2];
    float* out = (float*)d_out;
    float* Hsum = (float*)d_ws;   // M_ROWS*NC*4 = 786432 bytes

    hipMemsetAsync(d_ws, 0, (size_t)M_ROWS * NC * sizeof(float), stream);
    dim3 g1(M_ROWS / RPB, KSPLIT);
    mhc_gemm_kernel<<<g1, 256, 0, stream>>>(X, W, Hsum);
    mhc_apply_kernel<<<M_ROWS, 256, 0, stream>>>(X, Hsum, ab, out);
}

// Round 4
// 179.418 us; speedup vs baseline: 3.8648x; 3.8648x over previous
//
#include <hip/hip_runtime.h>
#include <math.h>
#include <stdint.h>

#define K_DIM 8192     // S*DIM
#define D_DIM 2048
#define M_ROWS 8192
#define N_W 32         // W columns (only 24 used in H)
#define NC 24
#define KSPLIT 8
#define KRANGE (K_DIM / KSPLIT)   // 1024 k per block
#define KC 256                    // k per staged W chunk
#define NSTEP (KC / 32)           // 8 k-steps (of 32) per chunk
#define NCHUNK (KRANGE / KC)      // 4 chunks per block

typedef short bf16x8 __attribute__((ext_vector_type(8)));
typedef float f32x4 __attribute__((ext_vector_type(4)));

union U32x4 { uint32_t u[4]; bf16x8 v; };

// ---------------------------------------------------------------------------
// Kernel 1: H[m, 0:24] partial GEMM via MFMA with bf16 hi/lo split.
//   fp32 x = hi(bf16,trunc) + lo(bf16,trunc of residual)  (~16 mantissa bits)
//   H = Xhi@Whi + Xhi@Wlo + Xlo@Whi   (Xlo@Wlo ~ 2^-32, dropped)
// Block = 256 thr (4 waves); wave owns a 16-row tile; block = 64 rows.
// Per 256-k chunk: coop-convert W[k0:k0+256][0:32] into LDS B-fragment
// buffer bfr[step][tile][hi/lo][lane][8] (32 KB), then 8 k-steps:
//   A-frag: lane loads 8 contiguous fp32 of its row (X[row][k0+(l>>4)*8+e]),
//   converts in-register; B-frags: 4x ds_read_b128 (stride-16B, conflict-free);
//   6 MFMA (2 col-tiles x 3 split terms) accumulating fp32.
// A/B use the SAME (lanegrp,e)->k map, so any k-permutation cancels; only the
// C/D layout matters: D[row=(l>>4)*4+reg][col=l&15]  [HW-verified].
// Partials combined by fp32 atomicAdd into Hsum (zeroed by memset).
// ---------------------------------------------------------------------------
__global__ __launch_bounds__(256) void mhc_gemm_kernel(
    const float* __restrict__ X, const float* __restrict__ W,
    float* __restrict__ Hsum)
{
    __shared__ __align__(16) unsigned short bfr[NSTEP][2][2][64][8]; // 32 KB
    const int t = threadIdx.x;
    const int l = t & 63;
    const int wv = t >> 6;
    const int rowbase = blockIdx.x * 64;
    const int kbase = blockIdx.y * KRANGE;

    f32x4 c0 = {0.f, 0.f, 0.f, 0.f};
    f32x4 c1 = {0.f, 0.f, 0.f, 0.f};

    const int arow = rowbase + wv * 16 + (l & 15);
    const float* __restrict__ xrow = X + (size_t)arow * K_DIM + ((l >> 4) * 8);
    const float4* __restrict__ Wg = reinterpret_cast<const float4*>(W);

    for (int c = 0; c < NCHUNK; ++c) {
        __syncthreads();   // previous chunk's compute done before overwrite
        // ---- prep: convert W chunk -> hi/lo B-fragments in LDS ----
#pragma unroll
        for (int q = 0; q < 8; ++q) {
            const int f  = q * 256 + t;          // float4 index in 256x8 chunk
            const int kk = f >> 3;               // k within chunk
            const int n4 = (f & 7) * 4;          // starting column
            const float4 wv4 = Wg[(size_t)(kbase + c * KC + kk) * 8 + (f & 7)];
            const float* we = reinterpret_cast<const float*>(&wv4);
            const int s  = kk >> 5;
            const int e  = kk & 7;
            const int lg = (kk >> 3) & 3;
#pragma unroll
            for (int j = 0; j < 4; ++j) {
                const int n = n4 + j;
                const uint32_t u = __float_as_uint(we[j]);
                const float hif = __uint_as_float(u & 0xFFFF0000u);
                const uint32_t ur = __float_as_uint(we[j] - hif);
                bfr[s][n >> 4][0][lg * 16 + (n & 15)][e] = (unsigned short)(u >> 16);
                bfr[s][n >> 4][1][lg * 16 + (n & 15)][e] = (unsigned short)(ur >> 16);
            }
        }
        __syncthreads();

        const float* xc = xrow + kbase + c * KC;
#pragma unroll
        for (int s = 0; s < NSTEP; ++s) {
            const float4 xa = *reinterpret_cast<const float4*>(xc + s * 32);
            const float4 xb = *reinterpret_cast<const float4*>(xc + s * 32 + 4);
            float xs[8];
            xs[0] = xa.x; xs[1] = xa.y; xs[2] = xa.z; xs[3] = xa.w;
            xs[4] = xb.x; xs[5] = xb.y; xs[6] = xb.z; xs[7] = xb.w;

            U32x4 ah, al;
#pragma unroll
            for (int p = 0; p < 4; ++p) {
                const uint32_t u0 = __float_as_uint(xs[2 * p]);
                const uint32_t u1 = __float_as_uint(xs[2 * p + 1]);
                const float h0 = __uint_as_float(u0 & 0xFFFF0000u);
                const float h1 = __uint_as_float(u1 & 0xFFFF0000u);
                const uint32_t r0 = __float_as_uint(xs[2 * p] - h0);
                const uint32_t r1 = __float_as_uint(xs[2 * p + 1] - h1);
                ah.u[p] = (u1 & 0xFFFF0000u) | (u0 >> 16);
                al.u[p] = (r1 & 0xFFFF0000u) | (r0 >> 16);
            }

            const bf16x8 bh0 = *reinterpret_cast<const bf16x8*>(&bfr[s][0][0][l][0]);
            const bf16x8 bl0 = *reinterpret_cast<const bf16x8*>(&bfr[s][0][1][l][0]);
            const bf16x8 bh1 = *reinterpret_cast<const bf16x8*>(&bfr[s][1][0][l][0]);
            const bf16x8 bl1 = *reinterpret_cast<const bf16x8*>(&bfr[s][1][1][l][0]);

            c0 = __builtin_amdgcn_mfma_f32_16x16x32_bf16(ah.v, bh0, c0, 0, 0, 0);
            c0 = __builtin_amdgcn_mfma_f32_16x16x32_bf16(al.v, bh0, c0, 0, 0, 0);
            c0 = __builtin_amdgcn_mfma_f32_16x16x32_bf16(ah.v, bl0, c0, 0, 0, 0);
            c1 = __builtin_amdgcn_mfma_f32_16x16x32_bf16(ah.v, bh1, c1, 0, 0, 0);
            c1 = __builtin_amdgcn_mfma_f32_16x16x32_bf16(al.v, bh1, c1, 0, 0, 0);
            c1 = __builtin_amdgcn_mfma_f32_16x16x32_bf16(ah.v, bl1, c1, 0, 0, 0);
        }
    }

    // ---- epilogue: D[row=(l>>4)*4+r][col=l&15]; atomic combine ----
    const int drow = rowbase + wv * 16 + (l >> 4) * 4;
    const int col = l & 15;
#pragma unroll
    for (int r = 0; r < 4; ++r)
        atomicAdd(&Hsum[(size_t)(drow + r) * NC + col], c0[r]);
    if (col < 8) {
#pragma unroll
        for (int r = 0; r < 4; ++r)
            atomicAdd(&Hsum[(size_t)(drow + r) * NC + 16 + col], c1[r]);
    }
}

// ---------------------------------------------------------------------------
// Kernel 2: params (transform + sinkhorn) + apply. One block per row.
// ---------------------------------------------------------------------------
__global__ __launch_bounds__(256) void mhc_apply_kernel(
    const float* __restrict__ X, const float* __restrict__ Hsum,
    const float* __restrict__ ab, float* __restrict__ out)
{
    __shared__ float pbuf[NC];
    const int row = blockIdx.x;
    const int t = threadIdx.x;

    if (t < 64) {
        const int lane = t;
        const float pl = (lane < NC) ? Hsum[(size_t)row * NC + lane] : 0.f;
        const float bias  = (lane < NC) ? ab[lane] : 0.f;
        const float scale = ab[(lane < 16) ? 24 : ((lane < 20) ? 25 : 26)];

        float vout;
        if (lane < 16) {
            vout = __expf(fmaf(scale, pl, bias));                 // exp(a_res*H+b)
        } else {
            vout = fmaf(scale, 1.f / (1.f + __expf(-pl)), bias);  // a*sigmoid(H)+b
        }

        // Sinkhorn on lanes 0..15: lane = s*4 + i.
        float p = vout;
        for (int it = 0; it < 20; ++it) {
            float rs = p + __shfl_xor(p, 1);
            rs += __shfl_xor(rs, 2);
            p = p / rs;
            float cs = p + __shfl_xor(p, 4);
            cs += __shfl_xor(cs, 8);
            p = p / cs;
        }
        if (lane < NC) pbuf[lane] = (lane < 16) ? p : vout;
    }
    __syncthreads();

    float hres[4][4], hpre[4], hpos[4];
#pragma unroll
    for (int i = 0; i < 16; ++i) hres[i >> 2][i & 3] = pbuf[i];
#pragma unroll
    for (int i = 0; i < 4; ++i) hpre[i] = pbuf[16 + i];
#pragma unroll
    for (int i = 0; i < 4; ++i) hpos[i] = pbuf[20 + i];

    const float4* __restrict__ Xr =
        reinterpret_cast<const float4*>(X + (size_t)row * K_DIM);
    float4* __restrict__ Or = reinterpret_cast<float4*>(out + (size_t)row * K_DIM);

#pragma unroll
    for (int q = 0; q < 2; ++q) {
        const int pos = t + q * 256;          // float4 index within a 2048-seg
        float4 xq[4];
#pragma unroll
        for (int i = 0; i < 4; ++i) xq[i] = Xr[i * (D_DIM / 4) + pos];

        float y[4];
#pragma unroll
        for (int e = 0; e < 4; ++e) {
            float s = 0.f;
#pragma unroll
            for (int i = 0; i < 4; ++i)
                s = fmaf(hpre[i], reinterpret_cast<const float*>(&xq[i])[e], s);
            y[e] = s;
        }

#pragma unroll
        for (int s = 0; s < 4; ++s) {
            float4 o;
            float* oe = reinterpret_cast<float*>(&o);
#pragma unroll
            for (int e = 0; e < 4; ++e) {
                float v = hpos[s] * y[e];
#pragma unroll
                for (int i = 0; i < 4; ++i)
                    v = fmaf(hres[s][i], reinterpret_cast<const float*>(&xq[i])[e], v);
                oe[e] = v;
            }
            Or[s * (D_DIM / 4) + pos] = o;
        }
    }
}

extern "C" void kernel_launch(void* const* d_in, const int* in_sizes, int n_in,
                              void* d_out, int out_size, void* d_ws, size_t ws_size,
                              hipStream_t stream) {
    const float* X  = (const float*)d_in[0];
    const float* W  = (const float*)d_in[1];
    const float* ab = (const float*)d_in[2];
    float* out = (float*)d_out;
    float* Hsum = (float*)d_ws;   // M_ROWS*NC*4 = 786432 bytes

    hipMemsetAsync(d_ws, 0, (size_t)M_ROWS * NC * sizeof(float), stream);
    dim3 g1(M_ROWS / 64, KSPLIT);
    mhc_gemm_kernel<<<g1, 256, 0, stream>>>(X, W, Hsum);
    mhc_apply_kernel<<<M_ROWS, 256, 0, stream>>>(X, Hsum, ab, out);
}